// Round 1
// baseline (196.326 us; speedup 1.0000x reference)
//
#include <hip/hip_runtime.h>
#include <math.h>

#define B_MOL 32
#define A_AT  1024
#define NF    128
#define N_AT  (B_MOL * A_AT)

// workspace layout (float offsets)
#define WS_K2P     0
#define WS_K2M     128
#define WS_WOUT    256
#define WS_C       384       // [0]=b_lin.k_plus, [1]=b_lin.k_minus
#define WS_NUMSUM  512       // 32 floats (zeroed)
#define WS_PREDSUM 544       // 32 floats (zeroed)
#define WS_NUM     1024
#define WS_EZWE    (WS_NUM + N_AT)
#define WS_PRED    (WS_EZWE + N_AT)

__device__ __forceinline__ float fast_rcp(float x) { return __builtin_amdgcn_rcpf(x); }
__device__ __forceinline__ float fast_rsq(float x) { return __builtin_amdgcn_rsqf(x); }
__device__ __forceinline__ float silu_f(float x) { return x * fast_rcp(1.f + __expf(-x)); }

__device__ __forceinline__ float wave_sum(float v) {
#pragma unroll
  for (int o = 32; o > 0; o >>= 1) v += __shfl_xor(v, o, 64);
  return v;
}

// ---- kernel 1: tiny precompute: k2_pm = W_lin @ k_pm ; wout_we = Wout @ w_e ; c_pm = b_lin . k_pm
__global__ void pre_kernel(const float* __restrict__ W_lin, const float* __restrict__ b_lin,
                           const float* __restrict__ k_plus, const float* __restrict__ k_minus,
                           const float* __restrict__ Wout, const float* __restrict__ w_e,
                           float* __restrict__ ws) {
  int g = threadIdx.x;  // 0..127
  float sp = 0.f, sm = 0.f, sw = 0.f;
  for (int f = 0; f < NF; f++) {
    float wl = W_lin[g * NF + f];
    sp = fmaf(wl, k_plus[f], sp);
    sm = fmaf(wl, k_minus[f], sm);
    sw = fmaf(Wout[g * NF + f], w_e[f], sw);
  }
  ws[WS_K2P + g] = sp;
  ws[WS_K2M + g] = sm;
  ws[WS_WOUT + g] = sw;
  if (g < 2) {
    const float* kk = (g == 0) ? k_plus : k_minus;
    float c = 0.f;
    for (int f = 0; f < NF; f++) c = fmaf(b_lin[f], kk[f], c);
    ws[WS_C + g] = c;
  }
}

// ---- kernel 2: per-atom softplus(arg) and e_z.w_e; per-molecule softplus sum (atomic)
__global__ __launch_bounds__(256) void attn_kernel(const float* __restrict__ e_z,
                                                   const float* __restrict__ charge,
                                                   const float* __restrict__ w_e,
                                                   float* __restrict__ ws) {
  int bx = blockIdx.x;         // 128 blocks = 32 mol * 4 chunks
  int mol = bx >> 2;
  int n = mol * A_AT + (bx & 3) * 256 + threadIdx.x;
  __shared__ float k2[NF], wesh[NF];
  float ch = charge[mol];
  if (threadIdx.x < NF) {
    const float* k2src = ws + (ch >= 0.f ? WS_K2P : WS_K2M);
    k2[threadIdx.x] = k2src[threadIdx.x];
    wesh[threadIdx.x] = w_e[threadIdx.x];
  }
  float cc = ws[WS_C + (ch >= 0.f ? 0 : 1)];
  __syncthreads();
  const float4* row = (const float4*)(e_z + (size_t)n * NF);
  float dk = 0.f, dw = 0.f;
#pragma unroll 8
  for (int i = 0; i < NF / 4; i++) {
    float4 v = row[i];
    dk = fmaf(v.x, k2[4*i+0], dk); dk = fmaf(v.y, k2[4*i+1], dk);
    dk = fmaf(v.z, k2[4*i+2], dk); dk = fmaf(v.w, k2[4*i+3], dk);
    dw = fmaf(v.x, wesh[4*i+0], dw); dw = fmaf(v.y, wesh[4*i+1], dw);
    dw = fmaf(v.z, wesh[4*i+2], dw); dw = fmaf(v.w, wesh[4*i+3], dw);
  }
  float arg = (dk + cc) * 0.08838834764831845f;  // 1/sqrt(128)
  float num = fmaxf(arg, 0.f) + log1pf(__expf(-fabsf(arg)));  // softplus, stable
  ws[WS_NUM + n] = num;
  ws[WS_EZWE + n] = dw;
  float s = wave_sum(num);
  if ((threadIdx.x & 63) == 0) atomicAdd(&ws[WS_NUMSUM + mol], s);
}

// ---- kernel 3: res_mlp (two 128x128 f32 GEMMs, BK=32 chunked LDS) + pred_q
__global__ __launch_bounds__(256) void mlp_kernel(const float* __restrict__ charge,
                                                  const float* __restrict__ v_plus,
                                                  const float* __restrict__ v_minus,
                                                  const float* __restrict__ Wr1,
                                                  const float* __restrict__ Wr2,
                                                  const int* __restrict__ z,
                                                  const float* __restrict__ qz_table,
                                                  float* __restrict__ ws) {
  int base = blockIdx.x * 128;   // 256 blocks * 128 atoms (always one molecule)
  int mol = base >> 10;
  int tid = threadIdx.x;
  int tx = tid & 15, ty = tid >> 4;     // tx: feature octet, ty: atom octet

  __shared__ float Wch[32 * 128];        // 16 KB, W rows chunk
  __shared__ float sxch[32 * 132];       // 16.5 KB, silu-input chunk, transposed [k][m], padded
  __shared__ float vsh[128], wout_sh[128], awsh[128], red[128], wred[4];

  float ch = charge[mol];
  if (tid < 128) {
    vsh[tid] = (ch >= 0.f) ? v_plus[tid] : v_minus[tid];
    wout_sh[tid] = ws[WS_WOUT + tid];
    float num = ws[WS_NUM + base + tid];
    awsh[tid] = ch * num / ws[WS_NUMSUM + mol];
    red[tid] = 0.f;
  }

  float acc[8][8], acc2[8][8];
#pragma unroll
  for (int i = 0; i < 8; i++)
#pragma unroll
    for (int j = 0; j < 8; j++) { acc[i][j] = 0.f; acc2[i][j] = 0.f; }

  // ---- GEMM1: h1 = silu(x) @ Wr1, x[m][k] = aw[m]*v[k]
  for (int c = 0; c < 4; c++) {
    __syncthreads();
    const float4* wsrc = (const float4*)(Wr1 + c * 32 * 128);
    float4* wdst = (float4*)Wch;
    for (int i = tid; i < 1024; i += 256) wdst[i] = wsrc[i];
    for (int i = tid; i < 4096; i += 256) {
      int kk = i >> 7, m = i & 127;
      sxch[kk * 132 + m] = silu_f(awsh[m] * vsh[c * 32 + kk]);
    }
    __syncthreads();
    for (int kk = 0; kk < 32; kk++) {
      float4 a0 = *(const float4*)&sxch[kk * 132 + ty * 8];
      float4 a1 = *(const float4*)&sxch[kk * 132 + ty * 8 + 4];
      float4 b0 = *(const float4*)&Wch[kk * 128 + tx * 8];
      float4 b1 = *(const float4*)&Wch[kk * 128 + tx * 8 + 4];
      float am[8] = {a0.x, a0.y, a0.z, a0.w, a1.x, a1.y, a1.z, a1.w};
      float bm[8] = {b0.x, b0.y, b0.z, b0.w, b1.x, b1.y, b1.z, b1.w};
#pragma unroll
      for (int mi = 0; mi < 8; mi++)
#pragma unroll
        for (int fj = 0; fj < 8; fj++)
          acc[mi][fj] = fmaf(am[mi], bm[fj], acc[mi][fj]);
    }
  }

  // ---- GEMM2: h2 = silu(h1) @ Wr2 ; silu(h1) chunks produced from acc registers
  for (int c = 0; c < 4; c++) {
    __syncthreads();
    const float4* wsrc = (const float4*)(Wr2 + c * 32 * 128);
    float4* wdst = (float4*)Wch;
    for (int i = tid; i < 1024; i += 256) wdst[i] = wsrc[i];
    if ((tx >> 2) == c) {                 // these 64 threads own f in [32c, 32c+32)
      int fl0 = (tx & 3) * 8;
#pragma unroll
      for (int fj = 0; fj < 8; fj++) {
        float4 s0 = make_float4(silu_f(acc[0][fj]), silu_f(acc[1][fj]),
                                silu_f(acc[2][fj]), silu_f(acc[3][fj]));
        float4 s1 = make_float4(silu_f(acc[4][fj]), silu_f(acc[5][fj]),
                                silu_f(acc[6][fj]), silu_f(acc[7][fj]));
        *(float4*)&sxch[(fl0 + fj) * 132 + ty * 8] = s0;
        *(float4*)&sxch[(fl0 + fj) * 132 + ty * 8 + 4] = s1;
      }
    }
    __syncthreads();
    for (int kk = 0; kk < 32; kk++) {
      float4 a0 = *(const float4*)&sxch[kk * 132 + ty * 8];
      float4 a1 = *(const float4*)&sxch[kk * 132 + ty * 8 + 4];
      float4 b0 = *(const float4*)&Wch[kk * 128 + tx * 8];
      float4 b1 = *(const float4*)&Wch[kk * 128 + tx * 8 + 4];
      float am[8] = {a0.x, a0.y, a0.z, a0.w, a1.x, a1.y, a1.z, a1.w};
      float bm[8] = {b0.x, b0.y, b0.z, b0.w, b1.x, b1.y, b1.z, b1.w};
#pragma unroll
      for (int mi = 0; mi < 8; mi++)
#pragma unroll
        for (int fj = 0; fj < 8; fj++)
          acc2[mi][fj] = fmaf(am[mi], bm[fj], acc2[mi][fj]);
    }
  }

  // ---- epilogue: pred = silu(x + h2) . wout_we + e_z.w_e + q_z_table[z]
  float partial[8];
#pragma unroll
  for (int mi = 0; mi < 8; mi++) partial[mi] = 0.f;
#pragma unroll
  for (int mi = 0; mi < 8; mi++) {
    float aw = awsh[ty * 8 + mi];
#pragma unroll
    for (int fj = 0; fj < 8; fj++) {
      int f = tx * 8 + fj;
      float s = silu_f(fmaf(aw, vsh[f], acc2[mi][fj]));
      partial[mi] = fmaf(s, wout_sh[f], partial[mi]);
    }
  }
#pragma unroll
  for (int mi = 0; mi < 8; mi++) atomicAdd(&red[ty * 8 + mi], partial[mi]);
  __syncthreads();
  float psum = 0.f;
  if (tid < 128) {
    int n = base + tid;
    float pred = red[tid] + ws[WS_EZWE + n] + qz_table[z[n]];
    ws[WS_PRED + n] = pred;
    psum = pred;
  }
  float wsum = wave_sum(psum);
  if ((tid & 63) == 0) wred[tid >> 6] = wsum;
  __syncthreads();
  if (tid == 0) atomicAdd(&ws[WS_PREDSUM + mol], wred[0] + wred[1] + wred[2] + wred[3]);
}

// ---- kernel 4: O(A^2) switched Coulomb. fs = sigmoid(1/arg - 1/(1-arg)), arg clamped.
__global__ __launch_bounds__(256) void pair_kernel(const float* __restrict__ xyz,
                                                   const float* __restrict__ charge,
                                                   const float* __restrict__ ws,
                                                   float* __restrict__ out) {
  int bx = blockIdx.x;         // 512 blocks = 32 mol * 16 i-chunks of 64
  int mol = bx >> 4;
  int sub = bx & 15;
  int tid = threadIdx.x;
  __shared__ float lx[1024], ly[1024], lz[1024], lq[1024];
  __shared__ float wred[4];
  float corr = (charge[mol] - ws[WS_PREDSUM + mol]) * (1.f / 1024.f);
  for (int j = tid; j < 1024; j += 256) {
    int g = mol * 1024 + j;
    lx[j] = xyz[3 * g + 0];
    ly[j] = xyz[3 * g + 1];
    lz[j] = xyz[3 * g + 2];
    lq[j] = ws[WS_PRED + g] + corr;
  }
  __syncthreads();
  int i = sub * 64 + (tid & 63);
  int jq = tid >> 6;           // 4 j-quarters of 256
  float xi = lx[i], yi = ly[i], zi = lz[i], qi = lq[i];
  float e = 0.f;
  int j0 = jq * 256;
#pragma unroll 4
  for (int j = j0; j < j0 + 256; j++) {
    float dx = xi - lx[j], dy = yi - ly[j], dz = zi - lz[j];
    float r2 = fmaf(dx, dx, fmaf(dy, dy, dz * dz));
    bool self = (j == i);
    float r2s = self ? 1.f : r2;
    float inv_r = fast_rsq(r2s);
    float r = r2s * inv_r;
    float arg = (r - 1.25f) * 0.4f;                 // (r - R_ON) / (R_OFF - R_ON)
    float argc = fminf(fmaxf(arg, 1e-6f), 1.f - 1e-6f);
    float t = fast_rcp(argc) - fast_rcp(1.f - argc);
    float fs = fast_rcp(1.f + __expf(-t));          // sigmoid(t)
    float coul = fmaf(fs, fast_rsq(r2s + 1.f), (1.f - fs) * inv_r);
    float qj = self ? 0.f : lq[j];
    e = fmaf(qj, coul, e);
  }
  e *= qi;
  float s = wave_sum(e);
  if ((tid & 63) == 0) wred[tid >> 6] = s;
  __syncthreads();
  if (tid == 0)
    atomicAdd(&out[mol], 166.0318f * (wred[0] + wred[1] + wred[2] + wred[3]));  // KE/2
}

extern "C" void kernel_launch(void* const* d_in, const int* in_sizes, int n_in,
                              void* d_out, int out_size, void* d_ws, size_t ws_size,
                              hipStream_t stream) {
  const float* e_z     = (const float*)d_in[0];
  const float* charge  = (const float*)d_in[1];
  const float* xyz     = (const float*)d_in[2];
  const float* W_lin   = (const float*)d_in[3];
  const float* b_lin   = (const float*)d_in[4];
  const float* k_plus  = (const float*)d_in[5];
  const float* k_minus = (const float*)d_in[6];
  const float* v_plus  = (const float*)d_in[7];
  const float* v_minus = (const float*)d_in[8];
  const float* Wr1     = (const float*)d_in[9];
  const float* Wr2     = (const float*)d_in[10];
  const float* Wout    = (const float*)d_in[11];
  const float* w_e     = (const float*)d_in[12];
  const float* qz      = (const float*)d_in[13];
  const int*   z       = (const int*)d_in[14];
  float* out = (float*)d_out;
  float* ws  = (float*)d_ws;

  hipMemsetAsync(ws + WS_NUMSUM, 0, 64 * sizeof(float), stream);  // numsum + predsum
  hipMemsetAsync(out, 0, B_MOL * sizeof(float), stream);

  pre_kernel<<<1, 128, 0, stream>>>(W_lin, b_lin, k_plus, k_minus, Wout, w_e, ws);
  attn_kernel<<<128, 256, 0, stream>>>(e_z, charge, w_e, ws);
  mlp_kernel<<<256, 256, 0, stream>>>(charge, v_plus, v_minus, Wr1, Wr2, z, qz, ws);
  pair_kernel<<<512, 256, 0, stream>>>(xyz, charge, ws, out);
}

// Round 2
// 170.413 us; speedup vs baseline: 1.1521x; 1.1521x over previous
//
#include <hip/hip_runtime.h>
#include <math.h>

#define B_MOL 32
#define A_AT  1024
#define NF    128
#define N_AT  (B_MOL * A_AT)

// workspace layout (float offsets)
#define WS_K2P     0
#define WS_K2M     128
#define WS_WOUT    256
#define WS_C       384       // [0]=b_lin.k_plus, [1]=b_lin.k_minus
#define WS_NUMSUM  512       // 32 floats (zeroed by pre_kernel)
#define WS_PREDSUM 544       // 32 floats (zeroed by pre_kernel)
#define WS_NUM     1024
#define WS_EZWE    (WS_NUM + N_AT)
#define WS_PRED    (WS_EZWE + N_AT)
#define WS_SIDX    (WS_PRED + N_AT)          // int[N_AT]: sorted->orig index
#define WS_SPOS    (WS_SIDX + N_AT)          // float4[N_AT]: sorted positions

__device__ __forceinline__ float fast_rcp(float x) { return __builtin_amdgcn_rcpf(x); }
__device__ __forceinline__ float fast_rsq(float x) { return __builtin_amdgcn_rsqf(x); }
__device__ __forceinline__ float silu_f(float x) { return x * fast_rcp(1.f + __expf(-x)); }

__device__ __forceinline__ float wave_sum(float v) {
#pragma unroll
  for (int o = 32; o > 0; o >>= 1) v += __shfl_xor(v, o, 64);
  return v;
}

// ---- kernel 1: precompute k2_pm = W_lin@k_pm ; wout_we = Wout@w_e ; c_pm ; zero accumulators
__global__ void pre_kernel(const float* __restrict__ W_lin, const float* __restrict__ b_lin,
                           const float* __restrict__ k_plus, const float* __restrict__ k_minus,
                           const float* __restrict__ Wout, const float* __restrict__ w_e,
                           float* __restrict__ ws, float* __restrict__ out) {
  int g = threadIdx.x;  // 0..127
  if (blockIdx.x == 0) {
    float sp = 0.f, sm = 0.f;
    for (int f = 0; f < NF; f++) {
      float wl = W_lin[g * NF + f];
      sp = fmaf(wl, k_plus[f], sp);
      sm = fmaf(wl, k_minus[f], sm);
    }
    ws[WS_K2P + g] = sp;
    ws[WS_K2M + g] = sm;
  } else {
    float sw = 0.f;
    for (int f = 0; f < NF; f++) sw = fmaf(Wout[g * NF + f], w_e[f], sw);
    ws[WS_WOUT + g] = sw;
    if (g < 2) {
      const float* kk = (g == 0) ? k_plus : k_minus;
      float c = 0.f;
      for (int f = 0; f < NF; f++) c = fmaf(b_lin[f], kk[f], c);
      ws[WS_C + g] = c;
    }
    if (g < 64) ws[WS_NUMSUM + g] = 0.f;   // numsum + predsum (contiguous)
    if (g < 32) out[g] = 0.f;
  }
}

// ---- kernel 2: per-molecule spatial counting sort (4x4x4 cells of 5.5 A)
__global__ __launch_bounds__(256) void sort_kernel(const float* __restrict__ xyz,
                                                   float* __restrict__ ws) {
  int mol = blockIdx.x, tid = threadIdx.x;
  __shared__ int hist[64], start[64];
  if (tid < 64) hist[tid] = 0;
  __syncthreads();
  float px[4], py[4], pz[4];
  int cell[4];
#pragma unroll
  for (int r = 0; r < 4; r++) {
    int j = tid + r * 256;
    const float* p = xyz + (size_t)(mol * A_AT + j) * 3;
    px[r] = p[0]; py[r] = p[1]; pz[r] = p[2];
    int cx = min(3, max(0, (int)(px[r] * (4.f / 22.f))));
    int cy = min(3, max(0, (int)(py[r] * (4.f / 22.f))));
    int cz = min(3, max(0, (int)(pz[r] * (4.f / 22.f))));
    cell[r] = cx * 16 + cy * 4 + cz;
    atomicAdd(&hist[cell[r]], 1);
  }
  __syncthreads();
  if (tid == 0) {
    int s = 0;
    for (int c = 0; c < 64; c++) { start[c] = s; s += hist[c]; }
  }
  __syncthreads();
  float4* spos = (float4*)(ws + WS_SPOS);
  int* sidx = (int*)ws + WS_SIDX;
#pragma unroll
  for (int r = 0; r < 4; r++) {
    int j = tid + r * 256;
    int off = atomicAdd(&start[cell[r]], 1);
    int g = mol * A_AT + off;
    spos[g] = make_float4(px[r], py[r], pz[r], 0.f);
    sidx[g] = j;
  }
}

// ---- kernel 3: per-atom softplus(arg) and e_z.w_e; per-molecule softplus sum
__global__ __launch_bounds__(128) void attn_kernel(const float* __restrict__ e_z,
                                                   const float* __restrict__ charge,
                                                   const float* __restrict__ w_e,
                                                   float* __restrict__ ws) {
  int bx = blockIdx.x;         // 256 blocks = 32 mol * 8 chunks of 128
  int mol = bx >> 3;
  int n = mol * A_AT + (bx & 7) * 128 + threadIdx.x;
  __shared__ float k2[NF], wesh[NF];
  float ch = charge[mol];
  const float* k2src = ws + (ch >= 0.f ? WS_K2P : WS_K2M);
  k2[threadIdx.x] = k2src[threadIdx.x];
  wesh[threadIdx.x] = w_e[threadIdx.x];
  float cc = ws[WS_C + (ch >= 0.f ? 0 : 1)];
  __syncthreads();
  const float4* row = (const float4*)(e_z + (size_t)n * NF);
  float dk = 0.f, dw = 0.f;
#pragma unroll 8
  for (int i = 0; i < NF / 4; i++) {
    float4 v = row[i];
    dk = fmaf(v.x, k2[4*i+0], dk); dk = fmaf(v.y, k2[4*i+1], dk);
    dk = fmaf(v.z, k2[4*i+2], dk); dk = fmaf(v.w, k2[4*i+3], dk);
    dw = fmaf(v.x, wesh[4*i+0], dw); dw = fmaf(v.y, wesh[4*i+1], dw);
    dw = fmaf(v.z, wesh[4*i+2], dw); dw = fmaf(v.w, wesh[4*i+3], dw);
  }
  float arg = (dk + cc) * 0.08838834764831845f;  // 1/sqrt(128)
  float num = fmaxf(arg, 0.f) + log1pf(__expf(-fabsf(arg)));  // stable softplus
  ws[WS_NUM + n] = num;
  ws[WS_EZWE + n] = dw;
  float s = wave_sum(num);
  if ((threadIdx.x & 63) == 0) atomicAdd(&ws[WS_NUMSUM + mol], s);
}

// ---- kernel 4: res_mlp. 32 atoms/block, 1024 blocks (4/CU), tile 2x8, conflict-free LDS.
__global__ __launch_bounds__(256, 4) void mlp_kernel(const float* __restrict__ charge,
                                                     const float* __restrict__ v_plus,
                                                     const float* __restrict__ v_minus,
                                                     const float* __restrict__ Wr1,
                                                     const float* __restrict__ Wr2,
                                                     const int* __restrict__ z,
                                                     const float* __restrict__ qz_table,
                                                     float* __restrict__ ws) {
  int base = blockIdx.x * 32;    // 32 atoms per block
  int mol = base >> 10;
  int tid = threadIdx.x;
  int tx = tid & 15, ty = tid >> 4;   // tx: feature group, ty: atom pair (0..15)

  __shared__ float Wch[32 * 128];     // 16 KB: W chunk [k][f]
  __shared__ float sxch[32 * 34];     // silu-input chunk, [k][m], pad 34 (8B-aligned pairs)
  __shared__ float vsh[128], wout_sh[128], awsh[32], pred_sh[32];

  float ch = charge[mol];
  if (tid < 128) {
    vsh[tid] = (ch >= 0.f) ? v_plus[tid] : v_minus[tid];
    wout_sh[tid] = ws[WS_WOUT + tid];
  }
  if (tid < 32) awsh[tid] = ch * ws[WS_NUM + base + tid] / ws[WS_NUMSUM + mol];

  float acc[2][8], acc2[2][8];
#pragma unroll
  for (int i = 0; i < 2; i++)
#pragma unroll
    for (int j = 0; j < 8; j++) { acc[i][j] = 0.f; acc2[i][j] = 0.f; }

  // thread's 8 output feats: f = tx*4+fj (fj 0..3), 64+tx*4+(fj-4) (fj 4..7)
  // ---- GEMM1: h1 = silu(aw[m]*v[k]) @ Wr1
  for (int c = 0; c < 4; c++) {
    __syncthreads();
    const float4* wsrc = (const float4*)(Wr1 + c * 32 * NF);
    float4* wdst = (float4*)Wch;
#pragma unroll
    for (int r = 0; r < 4; r++) wdst[tid + r * 256] = wsrc[tid + r * 256];
#pragma unroll
    for (int r = 0; r < 4; r++) {
      int idx = tid + r * 256;
      int kk = idx >> 5, m = idx & 31;
      sxch[kk * 34 + m] = silu_f(awsh[m] * vsh[c * 32 + kk]);
    }
    __syncthreads();
#pragma unroll 8
    for (int kk = 0; kk < 32; kk++) {
      float2 a = *(const float2*)&sxch[kk * 34 + ty * 2];
      float4 b0 = *(const float4*)&Wch[kk * 128 + tx * 4];
      float4 b1 = *(const float4*)&Wch[kk * 128 + 64 + tx * 4];
      float am[2] = {a.x, a.y};
      float bm[8] = {b0.x, b0.y, b0.z, b0.w, b1.x, b1.y, b1.z, b1.w};
#pragma unroll
      for (int mi = 0; mi < 2; mi++)
#pragma unroll
        for (int fj = 0; fj < 8; fj++)
          acc[mi][fj] = fmaf(am[mi], bm[fj], acc[mi][fj]);
    }
  }

  // ---- GEMM2: h2 = silu(h1) @ Wr2 ; A chunks produced from acc registers
  for (int c = 0; c < 4; c++) {
    __syncthreads();
    const float4* wsrc = (const float4*)(Wr2 + c * 32 * NF);
    float4* wdst = (float4*)Wch;
#pragma unroll
    for (int r = 0; r < 4; r++) wdst[tid + r * 256] = wsrc[tid + r * 256];
    // k in [32c,32c+32): owners are tx group (c&1), fj base (c<2?0:4)
    if ((tx >> 3) == (c & 1)) {
      int fb = (c < 2) ? 0 : 4;
#pragma unroll
      for (int f2 = 0; f2 < 4; f2++) {
        int k = (tx & 7) * 4 + f2;
        sxch[k * 34 + ty * 2 + 0] = silu_f(acc[0][fb + f2]);
        sxch[k * 34 + ty * 2 + 1] = silu_f(acc[1][fb + f2]);
      }
    }
    __syncthreads();
#pragma unroll 8
    for (int kk = 0; kk < 32; kk++) {
      float2 a = *(const float2*)&sxch[kk * 34 + ty * 2];
      float4 b0 = *(const float4*)&Wch[kk * 128 + tx * 4];
      float4 b1 = *(const float4*)&Wch[kk * 128 + 64 + tx * 4];
      float am[2] = {a.x, a.y};
      float bm[8] = {b0.x, b0.y, b0.z, b0.w, b1.x, b1.y, b1.z, b1.w};
#pragma unroll
      for (int mi = 0; mi < 2; mi++)
#pragma unroll
        for (int fj = 0; fj < 8; fj++)
          acc2[mi][fj] = fmaf(am[mi], bm[fj], acc2[mi][fj]);
    }
  }

  // ---- epilogue: pred = silu(x + h2) . wout_we + e_z.w_e + q_z_table[z]
  float partial[2] = {0.f, 0.f};
#pragma unroll
  for (int mi = 0; mi < 2; mi++) {
    float aw = awsh[ty * 2 + mi];
#pragma unroll
    for (int fj = 0; fj < 8; fj++) {
      int f = (fj < 4) ? (tx * 4 + fj) : (64 + tx * 4 + fj - 4);
      float s = silu_f(fmaf(aw, vsh[f], acc2[mi][fj]));
      partial[mi] = fmaf(s, wout_sh[f], partial[mi]);
    }
  }
  // reduce over the 16 tx lanes (consecutive within wave)
#pragma unroll
  for (int o = 8; o > 0; o >>= 1) {
    partial[0] += __shfl_xor(partial[0], o, 64);
    partial[1] += __shfl_xor(partial[1], o, 64);
  }
  if (tx == 0) {
#pragma unroll
    for (int mi = 0; mi < 2; mi++) {
      int m = ty * 2 + mi;
      int n = base + m;
      float pred = partial[mi] + ws[WS_EZWE + n] + qz_table[z[n]];
      ws[WS_PRED + n] = pred;
      pred_sh[m] = pred;
    }
  }
  __syncthreads();
  if (tid < 64) {
    float v = (tid < 32) ? pred_sh[tid] : 0.f;
    float s = wave_sum(v);
    if (tid == 0) atomicAdd(&ws[WS_PREDSUM + mol], s);
  }
}

// ---- kernel 5: O(A^2) Coulomb on sorted atoms; switch path only when wave-coherent-needed
__global__ __launch_bounds__(512) void pair_kernel(const float* __restrict__ xyz,
                                                   const float* __restrict__ charge,
                                                   float* __restrict__ ws,
                                                   float* __restrict__ out) {
  int bx = blockIdx.x;         // 512 blocks = 32 mol * 16 i-chunks of 64
  int mol = bx >> 4;
  int sub = bx & 15;
  int tid = threadIdx.x;
  __shared__ float4 posq[1024];  // 16 KB
  __shared__ float wred[8];
  const float4* spos = (const float4*)(ws + WS_SPOS);
  const int* sidx = (const int*)ws + WS_SIDX;
  float corr = (charge[mol] - ws[WS_PREDSUM + mol]) * (1.f / 1024.f);
  for (int j = tid; j < 1024; j += 512) {
    float4 p = spos[mol * 1024 + j];
    p.w = ws[WS_PRED + mol * 1024 + sidx[mol * 1024 + j]] + corr;
    posq[j] = p;
  }
  __syncthreads();
  int i = sub * 64 + (tid & 63);
  int jq = tid >> 6;           // 8 j-chunks of 128
  float4 me = posq[i];
  float e = 0.f;
  int j0 = jq * 128;
#pragma unroll 2
  for (int j = j0; j < j0 + 128; j++) {
    float4 p = posq[j];
    float dx = me.x - p.x, dy = me.y - p.y, dz = me.z - p.z;
    float r2 = fmaf(dx, dx, fmaf(dy, dy, dz * dz));
    bool self = (j == i);
    if (self) r2 = 1.0e8f;               // finite, fs=0, qj=0 anyway
    float qj = self ? 0.f : p.w;
    float inv_r = fast_rsq(r2);
    e = fmaf(qj, inv_r, e);              // plain Coulomb part, always
    if (__any(r2 < 14.0625f)) {          // R_OFF^2; expensive path, wave-coherent w/ sort
      float r = r2 * inv_r;
      float arg = (r - 1.25f) * 0.4f;    // (r - R_ON)/(R_OFF - R_ON)
      float argc = fminf(fmaxf(arg, 1e-6f), 1.f - 1e-6f);
      float t = fast_rcp(argc) - fast_rcp(1.f - argc);
      float fs = fast_rcp(1.f + __expf(-t));              // sigmoid; exp(inf)->fs=0 ok
      float delta = fs * (fast_rsq(r2 + 1.f) - inv_r);    // fs*(1/sqrt(r2+1) - 1/r)
      e = fmaf(qj, delta, e);
    }
  }
  e *= me.w;
  float s = wave_sum(e);
  if ((tid & 63) == 0) wred[tid >> 6] = s;
  __syncthreads();
  if (tid == 0) {
    float tot = 0.f;
#pragma unroll
    for (int k = 0; k < 8; k++) tot += wred[k];
    atomicAdd(&out[mol], 166.0318f * tot);   // KE_KCAL / 2 (we sum i!=j both ways)
  }
}

extern "C" void kernel_launch(void* const* d_in, const int* in_sizes, int n_in,
                              void* d_out, int out_size, void* d_ws, size_t ws_size,
                              hipStream_t stream) {
  const float* e_z     = (const float*)d_in[0];
  const float* charge  = (const float*)d_in[1];
  const float* xyz     = (const float*)d_in[2];
  const float* W_lin   = (const float*)d_in[3];
  const float* b_lin   = (const float*)d_in[4];
  const float* k_plus  = (const float*)d_in[5];
  const float* k_minus = (const float*)d_in[6];
  const float* v_plus  = (const float*)d_in[7];
  const float* v_minus = (const float*)d_in[8];
  const float* Wr1     = (const float*)d_in[9];
  const float* Wr2     = (const float*)d_in[10];
  const float* Wout    = (const float*)d_in[11];
  const float* w_e     = (const float*)d_in[12];
  const float* qz      = (const float*)d_in[13];
  const int*   z       = (const int*)d_in[14];
  float* out = (float*)d_out;
  float* ws  = (float*)d_ws;

  pre_kernel<<<2, 128, 0, stream>>>(W_lin, b_lin, k_plus, k_minus, Wout, w_e, ws, out);
  sort_kernel<<<32, 256, 0, stream>>>(xyz, ws);
  attn_kernel<<<256, 128, 0, stream>>>(e_z, charge, w_e, ws);
  mlp_kernel<<<1024, 256, 0, stream>>>(charge, v_plus, v_minus, Wr1, Wr2, z, qz, ws);
  pair_kernel<<<512, 512, 0, stream>>>(xyz, charge, ws, out);
}

// Round 3
// 158.999 us; speedup vs baseline: 1.2348x; 1.0718x over previous
//
#include <hip/hip_runtime.h>
#include <math.h>

#define B_MOL 32
#define A_AT  1024
#define NF    128
#define N_AT  (B_MOL * A_AT)

// workspace layout (float offsets)
#define WS_K2P     0
#define WS_K2M     128
#define WS_WOUT    256
#define WS_C       384       // [0]=b_lin.k_plus, [1]=b_lin.k_minus
#define WS_NUMSUM  512       // 32 floats (zeroed by pre_kernel)
#define WS_PREDSUM 544       // 32 floats (zeroed by pre_kernel)
#define WS_NUM     1024
#define WS_EZWE    (WS_NUM + N_AT)
#define WS_PRED    (WS_EZWE + N_AT)
#define WS_SIDX    (WS_PRED + N_AT)          // int[N_AT]: sorted->orig index
#define WS_SPOS    (WS_SIDX + N_AT)          // float4[N_AT]: sorted positions
#define WS_W1F     (WS_SPOS + 4 * N_AT)      // short[16384]: Wr1 bf16 MFMA-B frags (8192 floats)
#define WS_W2F     (WS_W1F + 8192)           // short[16384]: Wr2 bf16 MFMA-B frags

typedef short short8 __attribute__((ext_vector_type(8)));
typedef float floatx4 __attribute__((ext_vector_type(4)));

__device__ __forceinline__ float fast_rcp(float x) { return __builtin_amdgcn_rcpf(x); }
__device__ __forceinline__ float fast_rsq(float x) { return __builtin_amdgcn_rsqf(x); }
__device__ __forceinline__ float silu_f(float x) { return x * fast_rcp(1.f + __expf(-x)); }

__device__ __forceinline__ short f2bf(float x) {   // RNE f32 -> bf16
  unsigned u = __float_as_uint(x);
  u += 0x7fffu + ((u >> 16) & 1u);
  return (short)(u >> 16);
}

__device__ __forceinline__ float wave_sum(float v) {
#pragma unroll
  for (int o = 32; o > 0; o >>= 1) v += __shfl_xor(v, o, 64);
  return v;
}

// ---- kernel 1: blocks 0,1: swizzle Wr1/Wr2 into bf16 MFMA-B-fragment order.
//      block 2: k2_pm = W_lin@k_pm ; wout_we = Wout@w_e ; c_pm ; zero accumulators.
// B-frag for mfma_f32_16x16x32_bf16: lane holds B[k=(lane>>4)*8+j][n=lane&15], j=0..7.
// Storage: frag fi = nt*4+ks (k = ks*32 + ..., n = nt*16 + ...), shorts at fi*512+lane*8+j.
__global__ __launch_bounds__(256) void pre_kernel(const float* __restrict__ W_lin,
                                                  const float* __restrict__ b_lin,
                                                  const float* __restrict__ k_plus,
                                                  const float* __restrict__ k_minus,
                                                  const float* __restrict__ Wout,
                                                  const float* __restrict__ w_e,
                                                  const float* __restrict__ Wr1,
                                                  const float* __restrict__ Wr2,
                                                  float* __restrict__ ws,
                                                  float* __restrict__ out) {
  int tid = threadIdx.x;
  if (blockIdx.x < 2) {
    const float* W = (blockIdx.x == 0) ? Wr1 : Wr2;
    short* dst = (short*)(ws + ((blockIdx.x == 0) ? WS_W1F : WS_W2F));
#pragma unroll
    for (int it = 0; it < 8; it++) {
      int idx = it * 256 + tid;            // 2048 (fi,lane) pairs
      int fi = idx >> 6, lane = idx & 63;
      int nt = fi >> 2, ks = fi & 3;
      int q = lane >> 4, n15 = lane & 15;
      int k0 = ks * 32 + q * 8;
      int col = nt * 16 + n15;
#pragma unroll
      for (int j = 0; j < 8; j++)
        dst[fi * 512 + lane * 8 + j] = f2bf(W[(k0 + j) * NF + col]);
    }
  } else {
    if (tid < 128) {
      float sp = 0.f, sm = 0.f;
      for (int f = 0; f < NF; f++) {
        float wl = W_lin[tid * NF + f];
        sp = fmaf(wl, k_plus[f], sp);
        sm = fmaf(wl, k_minus[f], sm);
      }
      ws[WS_K2P + tid] = sp;
      ws[WS_K2M + tid] = sm;
      if (tid < 2) {
        const float* kk = (tid == 0) ? k_plus : k_minus;
        float c = 0.f;
        for (int f = 0; f < NF; f++) c = fmaf(b_lin[f], kk[f], c);
        ws[WS_C + tid] = c;
      }
    } else {
      int g = tid - 128;
      float sw = 0.f;
      for (int f = 0; f < NF; f++) sw = fmaf(Wout[g * NF + f], w_e[f], sw);
      ws[WS_WOUT + g] = sw;
      if (g < 64) ws[WS_NUMSUM + g] = 0.f;   // numsum + predsum (contiguous)
      if (g < 32) out[g] = 0.f;
    }
  }
}

// ---- kernel 2: per-molecule spatial counting sort (4x4x4 cells of 5.5 A)
__global__ __launch_bounds__(256) void sort_kernel(const float* __restrict__ xyz,
                                                   float* __restrict__ ws) {
  int mol = blockIdx.x, tid = threadIdx.x;
  __shared__ int hist[64], start[64];
  if (tid < 64) hist[tid] = 0;
  __syncthreads();
  float px[4], py[4], pz[4];
  int cell[4];
#pragma unroll
  for (int r = 0; r < 4; r++) {
    int j = tid + r * 256;
    const float* p = xyz + (size_t)(mol * A_AT + j) * 3;
    px[r] = p[0]; py[r] = p[1]; pz[r] = p[2];
    int cx = min(3, max(0, (int)(px[r] * (4.f / 22.f))));
    int cy = min(3, max(0, (int)(py[r] * (4.f / 22.f))));
    int cz = min(3, max(0, (int)(pz[r] * (4.f / 22.f))));
    cell[r] = cx * 16 + cy * 4 + cz;
    atomicAdd(&hist[cell[r]], 1);
  }
  __syncthreads();
  if (tid == 0) {
    int s = 0;
    for (int c = 0; c < 64; c++) { start[c] = s; s += hist[c]; }
  }
  __syncthreads();
  float4* spos = (float4*)(ws + WS_SPOS);
  int* sidx = (int*)ws + WS_SIDX;
#pragma unroll
  for (int r = 0; r < 4; r++) {
    int j = tid + r * 256;
    int off = atomicAdd(&start[cell[r]], 1);
    int g = mol * A_AT + off;
    spos[g] = make_float4(px[r], py[r], pz[r], 0.f);
    sidx[g] = j;
  }
}

// ---- kernel 3: softplus(arg) and e_z.w_e; 4 lanes per atom (memory-bound), 512 blocks
__global__ __launch_bounds__(256) void attn_kernel(const float* __restrict__ e_z,
                                                   const float* __restrict__ charge,
                                                   const float* __restrict__ w_e,
                                                   float* __restrict__ ws) {
  int tid = threadIdx.x;
  int t = blockIdx.x * 256 + tid;
  int n = t >> 2;                       // atom
  int part = t & 3;                     // quarter-row
  int mol = blockIdx.x >> 4;            // 64 atoms per block, one molecule
  __shared__ float k2[NF], wesh[NF];
  float ch = charge[mol];
  if (tid < 128) {
    const float* k2src = ws + (ch >= 0.f ? WS_K2P : WS_K2M);
    k2[tid] = k2src[tid];
    wesh[tid] = w_e[tid];
  }
  float cc = ws[WS_C + (ch >= 0.f ? 0 : 1)];
  __syncthreads();
  const float4* row = (const float4*)(e_z + (size_t)n * NF + part * 32);
  float dk = 0.f, dw = 0.f;
#pragma unroll 8
  for (int i = 0; i < 8; i++) {
    float4 v = row[i];
    int b = part * 32 + i * 4;
    dk = fmaf(v.x, k2[b+0], dk); dk = fmaf(v.y, k2[b+1], dk);
    dk = fmaf(v.z, k2[b+2], dk); dk = fmaf(v.w, k2[b+3], dk);
    dw = fmaf(v.x, wesh[b+0], dw); dw = fmaf(v.y, wesh[b+1], dw);
    dw = fmaf(v.z, wesh[b+2], dw); dw = fmaf(v.w, wesh[b+3], dw);
  }
  dk += __shfl_xor(dk, 1, 64); dk += __shfl_xor(dk, 2, 64);
  dw += __shfl_xor(dw, 1, 64); dw += __shfl_xor(dw, 2, 64);
  float num = 0.f;
  if (part == 0) {
    float arg = (dk + cc) * 0.08838834764831845f;  // 1/sqrt(128)
    num = fmaxf(arg, 0.f) + log1pf(__expf(-fabsf(arg)));  // stable softplus
    ws[WS_NUM + n] = num;
    ws[WS_EZWE + n] = dw;
  }
  float s = wave_sum(num);
  if ((tid & 63) == 0) atomicAdd(&ws[WS_NUMSUM + mol], s);
}

// ---- kernel 4: res_mlp via bf16 MFMA (16x16x32). 64 atoms/block, 512 blocks.
// GEMM1 A built in registers: A[m][k] = silu(aw[m]*v[k]). GEMM1->GEMM2 via padded LDS.
__global__ __launch_bounds__(256) void mlp_kernel(const float* __restrict__ charge,
                                                  const float* __restrict__ v_plus,
                                                  const float* __restrict__ v_minus,
                                                  const int* __restrict__ z,
                                                  const float* __restrict__ qz_table,
                                                  float* __restrict__ ws) {
  int base = blockIdx.x * 64;
  int mol = base >> 10;
  int tid = threadIdx.x;
  int w = tid >> 6;                 // wave 0..3, owns atoms base+w*16..+16
  int lane = tid & 63;
  int q = lane >> 4, l15 = lane & 15;

  __shared__ short wf[16384];       // 32 KB: one W's frags at a time
  __shared__ short a2s[4 * 16 * 136];  // 17 KB: silu(h1) per wave, [m][k], pad 8 shorts
  __shared__ float vsh[NF], wout_sh[NF], awsh[64], pred_sh[64];

  float ch = charge[mol];
  if (tid < 128) {
    vsh[tid] = (ch >= 0.f) ? v_plus[tid] : v_minus[tid];
    wout_sh[tid] = ws[WS_WOUT + tid];
  }
  if (tid < 64) awsh[tid] = ch * ws[WS_NUM + base + tid] / ws[WS_NUMSUM + mol];

  {  // stage Wr1 frags (32 KB)
    const float4* src = (const float4*)(ws + WS_W1F);
    float4* dst = (float4*)wf;
#pragma unroll
    for (int r = 0; r < 8; r++) dst[tid + r * 256] = src[tid + r * 256];
  }
  __syncthreads();

  float aw_m = awsh[w * 16 + l15];
  floatx4 acc1[8];
#pragma unroll
  for (int nt = 0; nt < 8; nt++) acc1[nt] = (floatx4)(0.f);

  // ---- GEMM1: h1 = silu(x) @ Wr1
#pragma unroll
  for (int ks = 0; ks < 4; ks++) {
    float4 va = *(const float4*)&vsh[ks * 32 + q * 8];
    float4 vb = *(const float4*)&vsh[ks * 32 + q * 8 + 4];
    short8 af;
    af[0] = f2bf(silu_f(aw_m * va.x)); af[1] = f2bf(silu_f(aw_m * va.y));
    af[2] = f2bf(silu_f(aw_m * va.z)); af[3] = f2bf(silu_f(aw_m * va.w));
    af[4] = f2bf(silu_f(aw_m * vb.x)); af[5] = f2bf(silu_f(aw_m * vb.y));
    af[6] = f2bf(silu_f(aw_m * vb.z)); af[7] = f2bf(silu_f(aw_m * vb.w));
#pragma unroll
    for (int nt = 0; nt < 8; nt++) {
      short8 bf = *(const short8*)&wf[(nt * 4 + ks) * 512 + lane * 8];
      acc1[nt] = __builtin_amdgcn_mfma_f32_16x16x32_bf16(af, bf, acc1[nt], 0, 0, 0);
    }
  }

  // write silu(h1) to LDS as bf16, [m][k] with +16B pad; C/D: row=q*4+r, col=l15
#pragma unroll
  for (int nt = 0; nt < 8; nt++) {
    int f = nt * 16 + l15;
#pragma unroll
    for (int r = 0; r < 4; r++)
      a2s[w * 2176 + (q * 4 + r) * 136 + f] = f2bf(silu_f(acc1[nt][r]));
  }
  __syncthreads();
  {  // restage Wr2 frags
    const float4* src = (const float4*)(ws + WS_W2F);
    float4* dst = (float4*)wf;
#pragma unroll
    for (int r = 0; r < 8; r++) dst[tid + r * 256] = src[tid + r * 256];
  }
  __syncthreads();

  floatx4 acc2[8];
#pragma unroll
  for (int nt = 0; nt < 8; nt++) acc2[nt] = (floatx4)(0.f);

  // ---- GEMM2: h2 = silu(h1) @ Wr2
#pragma unroll
  for (int ks = 0; ks < 4; ks++) {
    short8 af = *(const short8*)&a2s[w * 2176 + l15 * 136 + ks * 32 + q * 8];
#pragma unroll
    for (int nt = 0; nt < 8; nt++) {
      short8 bf = *(const short8*)&wf[(nt * 4 + ks) * 512 + lane * 8];
      acc2[nt] = __builtin_amdgcn_mfma_f32_16x16x32_bf16(af, bf, acc2[nt], 0, 0, 0);
    }
  }

  // ---- epilogue: pred = silu(x + h2) . wout_we + e_z.w_e + q_z_table[z]
  float awq[4], part[4];
#pragma unroll
  for (int r = 0; r < 4; r++) {
    awq[r] = awsh[w * 16 + q * 4 + r];
    part[r] = 0.f;
  }
#pragma unroll
  for (int nt = 0; nt < 8; nt++) {
    int f = nt * 16 + l15;
    float vv = vsh[f], ww = wout_sh[f];
#pragma unroll
    for (int r = 0; r < 4; r++) {
      float s = silu_f(fmaf(awq[r], vv, acc2[nt][r]));
      part[r] = fmaf(s, ww, part[r]);
    }
  }
#pragma unroll
  for (int r = 0; r < 4; r++) {
#pragma unroll
    for (int o = 1; o < 16; o <<= 1) part[r] += __shfl_xor(part[r], o, 64);
  }
  if (l15 == 0) {
#pragma unroll
    for (int r = 0; r < 4; r++) {
      int m = w * 16 + q * 4 + r;
      int n = base + m;
      float pred = part[r] + ws[WS_EZWE + n] + qz_table[z[n]];
      ws[WS_PRED + n] = pred;
      pred_sh[m] = pred;
    }
  }
  __syncthreads();
  if (tid < 64) {
    float s = wave_sum(pred_sh[tid]);
    if (tid == 0) atomicAdd(&ws[WS_PREDSUM + mol], s);
  }
}

// ---- kernel 5: O(A^2) Coulomb on sorted atoms; switch path only when wave-coherent-needed
__global__ __launch_bounds__(512) void pair_kernel(const float* __restrict__ xyz,
                                                   const float* __restrict__ charge,
                                                   float* __restrict__ ws,
                                                   float* __restrict__ out) {
  int bx = blockIdx.x;         // 512 blocks = 32 mol * 16 i-chunks of 64
  int mol = bx >> 4;
  int sub = bx & 15;
  int tid = threadIdx.x;
  __shared__ float4 posq[1024];  // 16 KB
  __shared__ float wred[8];
  const float4* spos = (const float4*)(ws + WS_SPOS);
  const int* sidx = (const int*)ws + WS_SIDX;
  float corr = (charge[mol] - ws[WS_PREDSUM + mol]) * (1.f / 1024.f);
  for (int j = tid; j < 1024; j += 512) {
    float4 p = spos[mol * 1024 + j];
    p.w = ws[WS_PRED + mol * 1024 + sidx[mol * 1024 + j]] + corr;
    posq[j] = p;
  }
  __syncthreads();
  int i = sub * 64 + (tid & 63);
  int jq = tid >> 6;           // 8 j-chunks of 128
  float4 me = posq[i];
  float e = 0.f;
  int j0 = jq * 128;
#pragma unroll 2
  for (int j = j0; j < j0 + 128; j++) {
    float4 p = posq[j];
    float dx = me.x - p.x, dy = me.y - p.y, dz = me.z - p.z;
    float r2 = fmaf(dx, dx, fmaf(dy, dy, dz * dz));
    bool self = (j == i);
    if (self) r2 = 1.0e8f;               // finite, fs=0, qj=0 anyway
    float qj = self ? 0.f : p.w;
    float inv_r = fast_rsq(r2);
    e = fmaf(qj, inv_r, e);              // plain Coulomb part, always
    if (__any(r2 < 14.0625f)) {          // R_OFF^2; expensive path, wave-coherent w/ sort
      float r = r2 * inv_r;
      float arg = (r - 1.25f) * 0.4f;    // (r - R_ON)/(R_OFF - R_ON)
      float argc = fminf(fmaxf(arg, 1e-6f), 1.f - 1e-6f);
      float t = fast_rcp(argc) - fast_rcp(1.f - argc);
      float fs = fast_rcp(1.f + __expf(-t));              // sigmoid; exp(inf)->fs=0 ok
      float delta = fs * (fast_rsq(r2 + 1.f) - inv_r);    // fs*(1/sqrt(r2+1) - 1/r)
      e = fmaf(qj, delta, e);
    }
  }
  e *= me.w;
  float s = wave_sum(e);
  if ((tid & 63) == 0) wred[tid >> 6] = s;
  __syncthreads();
  if (tid == 0) {
    float tot = 0.f;
#pragma unroll
    for (int k = 0; k < 8; k++) tot += wred[k];
    atomicAdd(&out[mol], 166.0318f * tot);   // KE_KCAL / 2 (we sum i!=j both ways)
  }
}

extern "C" void kernel_launch(void* const* d_in, const int* in_sizes, int n_in,
                              void* d_out, int out_size, void* d_ws, size_t ws_size,
                              hipStream_t stream) {
  const float* e_z     = (const float*)d_in[0];
  const float* charge  = (const float*)d_in[1];
  const float* xyz     = (const float*)d_in[2];
  const float* W_lin   = (const float*)d_in[3];
  const float* b_lin   = (const float*)d_in[4];
  const float* k_plus  = (const float*)d_in[5];
  const float* k_minus = (const float*)d_in[6];
  const float* v_plus  = (const float*)d_in[7];
  const float* v_minus = (const float*)d_in[8];
  const float* Wr1     = (const float*)d_in[9];
  const float* Wr2     = (const float*)d_in[10];
  const float* Wout    = (const float*)d_in[11];
  const float* w_e     = (const float*)d_in[12];
  const float* qz      = (const float*)d_in[13];
  const int*   z       = (const int*)d_in[14];
  float* out = (float*)d_out;
  float* ws  = (float*)d_ws;

  pre_kernel<<<3, 256, 0, stream>>>(W_lin, b_lin, k_plus, k_minus, Wout, w_e,
                                    Wr1, Wr2, ws, out);
  sort_kernel<<<32, 256, 0, stream>>>(xyz, ws);
  attn_kernel<<<512, 256, 0, stream>>>(e_z, charge, w_e, ws);
  mlp_kernel<<<512, 256, 0, stream>>>(charge, v_plus, v_minus, z, qz, ws);
  pair_kernel<<<512, 512, 0, stream>>>(xyz, charge, ws, out);
}

// Round 4
// 147.865 us; speedup vs baseline: 1.3277x; 1.0753x over previous
//
#include <hip/hip_runtime.h>
#include <math.h>

#define B_MOL 32
#define A_AT  1024
#define NF    128
#define N_AT  (B_MOL * A_AT)

// workspace layout (float offsets)
#define WS_K2P     0
#define WS_K2M     128
#define WS_WOUT    256
#define WS_C       384       // [0]=b_lin.k_plus, [1]=b_lin.k_minus
#define WS_NUMSUM  512       // 32 floats (zeroed by setup)
#define WS_PREDSUM 544       // 32 floats (zeroed by setup)
#define WS_NUM     1024
#define WS_EZWE    (WS_NUM + N_AT)
#define WS_PRED    (WS_EZWE + N_AT)
#define WS_SIDX    (WS_PRED + N_AT)          // int[N_AT]: sorted->orig index
#define WS_SPOS    (WS_SIDX + N_AT)          // float4[N_AT]: sorted positions
#define WS_W1F     (WS_SPOS + 4 * N_AT)      // short[16384]: Wr1 bf16 MFMA-B frags
#define WS_W2F     (WS_W1F + 8192)           // short[16384]: Wr2 bf16 MFMA-B frags

typedef short short8 __attribute__((ext_vector_type(8)));
typedef float floatx4 __attribute__((ext_vector_type(4)));

__device__ __forceinline__ float fast_rcp(float x) { return __builtin_amdgcn_rcpf(x); }
__device__ __forceinline__ float fast_rsq(float x) { return __builtin_amdgcn_rsqf(x); }
__device__ __forceinline__ float silu_f(float x) { return x * fast_rcp(1.f + __expf(-x)); }

__device__ __forceinline__ short f2bf(float x) {   // RNE f32 -> bf16
  unsigned u = __float_as_uint(x);
  u += 0x7fffu + ((u >> 16) & 1u);
  return (short)(u >> 16);
}

__device__ __forceinline__ float wave_sum(float v) {
#pragma unroll
  for (int o = 32; o > 0; o >>= 1) v += __shfl_xor(v, o, 64);
  return v;
}

// ---- kernel 1 (setup): blocks 0-31 sort; 32/33 swizzle Wr1/Wr2 (coalesced reads);
//      block 34: k2_pm, c_pm, wout_we, zero accumulators + out.
// B-frag (mfma_f32_16x16x32_bf16): lane q*16+n15 holds B[k=ks*32+q*8+j][n=nt*16+n15],
// stored at (nt*4+ks)*512 + lane*8 + j.
__global__ __launch_bounds__(256) void setup_kernel(const float* __restrict__ xyz,
                                                    const float* __restrict__ W_lin,
                                                    const float* __restrict__ b_lin,
                                                    const float* __restrict__ k_plus,
                                                    const float* __restrict__ k_minus,
                                                    const float* __restrict__ Wout,
                                                    const float* __restrict__ w_e,
                                                    const float* __restrict__ Wr1,
                                                    const float* __restrict__ Wr2,
                                                    float* __restrict__ ws,
                                                    float* __restrict__ out) {
  int bx = blockIdx.x, tid = threadIdx.x;
  if (bx < 32) {                 // per-molecule spatial counting sort, 4x4x4 cells
    int mol = bx;
    __shared__ int hist[64], start[64];
    if (tid < 64) hist[tid] = 0;
    __syncthreads();
    float px[4], py[4], pz[4];
    int cell[4];
#pragma unroll
    for (int r = 0; r < 4; r++) {
      int j = tid + r * 256;
      const float* p = xyz + (size_t)(mol * A_AT + j) * 3;
      px[r] = p[0]; py[r] = p[1]; pz[r] = p[2];
      int cx = min(3, max(0, (int)(px[r] * (4.f / 22.f))));
      int cy = min(3, max(0, (int)(py[r] * (4.f / 22.f))));
      int cz = min(3, max(0, (int)(pz[r] * (4.f / 22.f))));
      cell[r] = cx * 16 + cy * 4 + cz;
      atomicAdd(&hist[cell[r]], 1);
    }
    __syncthreads();
    if (tid == 0) {
      int s = 0;
      for (int c = 0; c < 64; c++) { start[c] = s; s += hist[c]; }
    }
    __syncthreads();
    float4* spos = (float4*)(ws + WS_SPOS);
    int* sidx = (int*)ws + WS_SIDX;
#pragma unroll
    for (int r = 0; r < 4; r++) {
      int j = tid + r * 256;
      int off = atomicAdd(&start[cell[r]], 1);
      int g = mol * A_AT + off;
      spos[g] = make_float4(px[r], py[r], pz[r], 0.f);
      sidx[g] = j;
    }
  } else if (bx < 34) {          // weight swizzle, coalesced float4 reads
    const float* W = (bx == 32) ? Wr1 : Wr2;
    short* dst = (short*)(ws + ((bx == 32) ? WS_W1F : WS_W2F));
#pragma unroll
    for (int it = 0; it < 16; it++) {
      int idx = it * 256 + tid;        // float4 index over 128x128
      int k = idx >> 5;
      int c0 = (idx & 31) * 4;
      float4 v = ((const float4*)W)[idx];
      int ks = k >> 5, q = (k & 31) >> 3, j = k & 7;
      float vv[4] = {v.x, v.y, v.z, v.w};
#pragma unroll
      for (int e = 0; e < 4; e++) {
        int col = c0 + e;
        int fi = (col >> 4) * 4 + ks;
        int lane = q * 16 + (col & 15);
        dst[fi * 512 + lane * 8 + j] = f2bf(vv[e]);
      }
    }
  } else {                       // constants
    if (tid < 128) {
      float sp = 0.f, sm = 0.f;
      for (int f = 0; f < NF; f++) {
        float wl = W_lin[tid * NF + f];
        sp = fmaf(wl, k_plus[f], sp);
        sm = fmaf(wl, k_minus[f], sm);
      }
      ws[WS_K2P + tid] = sp;
      ws[WS_K2M + tid] = sm;
      if (tid < 2) {
        const float* kk = (tid == 0) ? k_plus : k_minus;
        float c = 0.f;
        for (int f = 0; f < NF; f++) c = fmaf(b_lin[f], kk[f], c);
        ws[WS_C + tid] = c;
      }
    } else {
      int g = tid - 128;
      float sw = 0.f;
      for (int f = 0; f < NF; f++) sw = fmaf(Wout[g * NF + f], w_e[f], sw);
      ws[WS_WOUT + g] = sw;
      if (g < 64) ws[WS_NUMSUM + g] = 0.f;   // numsum + predsum (contiguous)
      if (g < 32) out[g] = 0.f;
    }
  }
}

// ---- kernel 2: softplus(arg) & e_z.w_e, fully coalesced (32 lanes per 512 B row)
__global__ __launch_bounds__(256) void attn_kernel(const float* __restrict__ e_z,
                                                   const float* __restrict__ charge,
                                                   const float* __restrict__ w_e,
                                                   float* __restrict__ ws) {
  int bx = blockIdx.x;          // 512 blocks = 32 mol * 16 chunks of 64 atoms
  int mol = bx >> 4;
  int base = bx * 64;
  int tid = threadIdx.x;
  int w = tid >> 6, l = tid & 63, half = l >> 5, l31 = l & 31;
  __shared__ float k2[NF], wesh[NF], numred[4];
  float ch = charge[mol];
  if (tid < 128) {
    const float* k2src = ws + (ch >= 0.f ? WS_K2P : WS_K2M);
    k2[tid] = k2src[tid];
    wesh[tid] = w_e[tid];
  }
  float cc = ws[WS_C + (ch >= 0.f ? 0 : 1)];
  __syncthreads();
  int b = l31 * 4;
  float k0 = k2[b], k1 = k2[b+1], k2v = k2[b+2], k3 = k2[b+3];
  float w0 = wesh[b], w1 = wesh[b+1], w2 = wesh[b+2], w3 = wesh[b+3];
  float wavenum = 0.f;
#pragma unroll
  for (int it = 0; it < 8; it++) {
    int m = it * 8 + w * 2 + half;      // local atom 0..63
    int n = base + m;
    float4 v = *((const float4*)(e_z + (size_t)n * NF) + l31);  // coalesced 1KB/wave
    float dk = v.x*k0; dk = fmaf(v.y, k1, dk); dk = fmaf(v.z, k2v, dk); dk = fmaf(v.w, k3, dk);
    float dw = v.x*w0; dw = fmaf(v.y, w1, dw); dw = fmaf(v.z, w2, dw); dw = fmaf(v.w, w3, dw);
#pragma unroll
    for (int o = 1; o < 32; o <<= 1) {
      dk += __shfl_xor(dk, o, 64);
      dw += __shfl_xor(dw, o, 64);
    }
    if (l31 == 0) {
      float arg = (dk + cc) * 0.08838834764831845f;   // 1/sqrt(128)
      float num = fmaxf(arg, 0.f) + log1pf(__expf(-fabsf(arg)));
      ws[WS_NUM + n] = num;
      ws[WS_EZWE + n] = dw;
      wavenum += num;
    }
  }
  wavenum += __shfl_xor(wavenum, 32, 64);   // lane0 + lane32
  if (l == 0) numred[w] = wavenum;
  __syncthreads();
  if (tid == 0)
    atomicAdd(&ws[WS_NUMSUM + mol], numred[0] + numred[1] + numred[2] + numred[3]);
}

// ---- kernel 3: res_mlp via bf16 MFMA (16x16x32). 64 atoms/block, 512 blocks.
__global__ __launch_bounds__(256) void mlp_kernel(const float* __restrict__ charge,
                                                  const float* __restrict__ v_plus,
                                                  const float* __restrict__ v_minus,
                                                  const int* __restrict__ z,
                                                  const float* __restrict__ qz_table,
                                                  float* __restrict__ ws) {
  int base = blockIdx.x * 64;
  int mol = base >> 10;
  int tid = threadIdx.x;
  int w = tid >> 6;
  int lane = tid & 63;
  int q = lane >> 4, l15 = lane & 15;

  __shared__ short wf[16384];            // 32 KB, one W's frags at a time
  __shared__ short a2s[4 * 16 * 136];    // 17 KB, silu(h1) per wave, [m][k], padded
  __shared__ float vsh[NF], wout_sh[NF], awsh[64], pred_sh[64];

  float ch = charge[mol];
  if (tid < 128) {
    vsh[tid] = (ch >= 0.f) ? v_plus[tid] : v_minus[tid];
    wout_sh[tid] = ws[WS_WOUT + tid];
  }
  if (tid < 64) awsh[tid] = ch * ws[WS_NUM + base + tid] / ws[WS_NUMSUM + mol];

  {
    const float4* src = (const float4*)(ws + WS_W1F);
    float4* dst = (float4*)wf;
#pragma unroll
    for (int r = 0; r < 8; r++) dst[tid + r * 256] = src[tid + r * 256];
  }
  __syncthreads();

  float aw_m = awsh[w * 16 + l15];
  floatx4 acc1[8];
#pragma unroll
  for (int nt = 0; nt < 8; nt++) acc1[nt] = (floatx4)(0.f);

  // GEMM1: h1 = silu(aw*v) @ Wr1 ; A built in registers
#pragma unroll
  for (int ks = 0; ks < 4; ks++) {
    float4 va = *(const float4*)&vsh[ks * 32 + q * 8];
    float4 vb = *(const float4*)&vsh[ks * 32 + q * 8 + 4];
    short8 af;
    af[0] = f2bf(silu_f(aw_m * va.x)); af[1] = f2bf(silu_f(aw_m * va.y));
    af[2] = f2bf(silu_f(aw_m * va.z)); af[3] = f2bf(silu_f(aw_m * va.w));
    af[4] = f2bf(silu_f(aw_m * vb.x)); af[5] = f2bf(silu_f(aw_m * vb.y));
    af[6] = f2bf(silu_f(aw_m * vb.z)); af[7] = f2bf(silu_f(aw_m * vb.w));
#pragma unroll
    for (int nt = 0; nt < 8; nt++) {
      short8 bf = *(const short8*)&wf[(nt * 4 + ks) * 512 + lane * 8];
      acc1[nt] = __builtin_amdgcn_mfma_f32_16x16x32_bf16(af, bf, acc1[nt], 0, 0, 0);
    }
  }

  // silu(h1) -> LDS bf16 [m][k] (+pad); C/D layout: row=q*4+r, col=l15
#pragma unroll
  for (int nt = 0; nt < 8; nt++) {
    int f = nt * 16 + l15;
#pragma unroll
    for (int r = 0; r < 4; r++)
      a2s[w * 2176 + (q * 4 + r) * 136 + f] = f2bf(silu_f(acc1[nt][r]));
  }
  __syncthreads();
  {
    const float4* src = (const float4*)(ws + WS_W2F);
    float4* dst = (float4*)wf;
#pragma unroll
    for (int r = 0; r < 8; r++) dst[tid + r * 256] = src[tid + r * 256];
  }
  __syncthreads();

  floatx4 acc2[8];
#pragma unroll
  for (int nt = 0; nt < 8; nt++) acc2[nt] = (floatx4)(0.f);

  // GEMM2: h2 = silu(h1) @ Wr2
#pragma unroll
  for (int ks = 0; ks < 4; ks++) {
    short8 af = *(const short8*)&a2s[w * 2176 + l15 * 136 + ks * 32 + q * 8];
#pragma unroll
    for (int nt = 0; nt < 8; nt++) {
      short8 bf = *(const short8*)&wf[(nt * 4 + ks) * 512 + lane * 8];
      acc2[nt] = __builtin_amdgcn_mfma_f32_16x16x32_bf16(af, bf, acc2[nt], 0, 0, 0);
    }
  }

  // epilogue: pred = silu(x + h2) . wout_we + e_z.w_e + q_z_table[z]
  float awq[4], part[4];
#pragma unroll
  for (int r = 0; r < 4; r++) {
    awq[r] = awsh[w * 16 + q * 4 + r];
    part[r] = 0.f;
  }
#pragma unroll
  for (int nt = 0; nt < 8; nt++) {
    int f = nt * 16 + l15;
    float vv = vsh[f], ww = wout_sh[f];
#pragma unroll
    for (int r = 0; r < 4; r++) {
      float s = silu_f(fmaf(awq[r], vv, acc2[nt][r]));
      part[r] = fmaf(s, ww, part[r]);
    }
  }
#pragma unroll
  for (int r = 0; r < 4; r++) {
#pragma unroll
    for (int o = 1; o < 16; o <<= 1) part[r] += __shfl_xor(part[r], o, 64);
  }
  if (l15 == 0) {
#pragma unroll
    for (int r = 0; r < 4; r++) {
      int m = w * 16 + q * 4 + r;
      int n = base + m;
      float pred = part[r] + ws[WS_EZWE + n] + qz_table[z[n]];
      ws[WS_PRED + n] = pred;
      pred_sh[m] = pred;
    }
  }
  __syncthreads();
  if (tid < 64) {
    float s = wave_sum(pred_sh[tid]);
    if (tid == 0) atomicAdd(&ws[WS_PREDSUM + mol], s);
  }
}

// ---- kernel 4: triangle-decomposed switched Coulomb on sorted atoms.
// Block (mol, s): i = s*64+lane; wave w handles j-chunks c = s+w, s+w+4, ...
__global__ __launch_bounds__(256) void pair_kernel(const float* __restrict__ charge,
                                                   float* __restrict__ ws,
                                                   float* __restrict__ out) {
  int bx = blockIdx.x;         // 512 = 32 mol * 16 i-chunks
  int mol = bx >> 4;
  int s = bx & 15;
  int tid = threadIdx.x;
  int w = tid >> 6, lane = tid & 63;
  __shared__ float4 posq[1024];   // 16 KB
  __shared__ float wred[4];
  const float4* spos = (const float4*)(ws + WS_SPOS);
  const int* sidx = (const int*)ws + WS_SIDX;
  float corr = (charge[mol] - ws[WS_PREDSUM + mol]) * (1.f / 1024.f);
  for (int j = tid; j < 1024; j += 256) {
    float4 p = spos[mol * 1024 + j];
    p.w = ws[WS_PRED + mol * 1024 + sidx[mol * 1024 + j]] + corr;
    posq[j] = p;
  }
  __syncthreads();
  int i = s * 64 + lane;
  float4 me = posq[i];
  float e = 0.f;
  for (int c = s + w; c < 16; c += 4) {
    int j0 = c * 64;
    if (c == s) {                       // diagonal chunk: mask j <= i
#pragma unroll 4
      for (int j = j0; j < j0 + 64; j++) {
        float4 p = posq[j];
        float dx = me.x - p.x, dy = me.y - p.y, dz = me.z - p.z;
        float r2 = fmaf(dx, dx, fmaf(dy, dy, dz * dz));
        bool skip = (j <= i);
        float r2s = skip ? 1.0e8f : r2;
        float qj = skip ? 0.f : p.w;
        float inv_r = fast_rsq(r2s);
        e = fmaf(qj, inv_r, e);
        if (__any(r2s < 14.0625f)) {    // R_OFF^2
          float r = r2s * inv_r;
          float arg = (r - 1.25f) * 0.4f;
          float argc = fminf(fmaxf(arg, 1e-6f), 1.f - 1e-6f);
          float t = fast_rcp(argc) - fast_rcp(1.f - argc);
          float fs = fast_rcp(1.f + __expf(-t));
          float delta = fs * (fast_rsq(r2s + 1.f) - inv_r);
          e = fmaf(qj, delta, e);
        }
      }
    } else {
#pragma unroll 4
      for (int j = j0; j < j0 + 64; j++) {
        float4 p = posq[j];
        float dx = me.x - p.x, dy = me.y - p.y, dz = me.z - p.z;
        float r2 = fmaf(dx, dx, fmaf(dy, dy, dz * dz));
        float qj = p.w;
        float inv_r = fast_rsq(r2);
        e = fmaf(qj, inv_r, e);
        if (__any(r2 < 14.0625f)) {
          float r = r2 * inv_r;
          float arg = (r - 1.25f) * 0.4f;
          float argc = fminf(fmaxf(arg, 1e-6f), 1.f - 1e-6f);
          float t = fast_rcp(argc) - fast_rcp(1.f - argc);
          float fs = fast_rcp(1.f + __expf(-t));
          float delta = fs * (fast_rsq(r2 + 1.f) - inv_r);
          e = fmaf(qj, delta, e);
        }
      }
    }
  }
  e *= me.w;
  float sred = wave_sum(e);
  if (lane == 0) wred[w] = sred;
  __syncthreads();
  if (tid == 0)
    atomicAdd(&out[mol], 332.0636f * (wred[0] + wred[1] + wred[2] + wred[3]));
}

extern "C" void kernel_launch(void* const* d_in, const int* in_sizes, int n_in,
                              void* d_out, int out_size, void* d_ws, size_t ws_size,
                              hipStream_t stream) {
  const float* e_z     = (const float*)d_in[0];
  const float* charge  = (const float*)d_in[1];
  const float* xyz     = (const float*)d_in[2];
  const float* W_lin   = (const float*)d_in[3];
  const float* b_lin   = (const float*)d_in[4];
  const float* k_plus  = (const float*)d_in[5];
  const float* k_minus = (const float*)d_in[6];
  const float* v_plus  = (const float*)d_in[7];
  const float* v_minus = (const float*)d_in[8];
  const float* Wr1     = (const float*)d_in[9];
  const float* Wr2     = (const float*)d_in[10];
  const float* Wout    = (const float*)d_in[11];
  const float* w_e     = (const float*)d_in[12];
  const float* qz      = (const float*)d_in[13];
  const int*   z       = (const int*)d_in[14];
  float* out = (float*)d_out;
  float* ws  = (float*)d_ws;

  setup_kernel<<<35, 256, 0, stream>>>(xyz, W_lin, b_lin, k_plus, k_minus,
                                       Wout, w_e, Wr1, Wr2, ws, out);
  attn_kernel<<<512, 256, 0, stream>>>(e_z, charge, w_e, ws);
  mlp_kernel<<<512, 256, 0, stream>>>(charge, v_plus, v_minus, z, qz, ws);
  pair_kernel<<<512, 256, 0, stream>>>(charge, ws, out);
}